// Round 6
// baseline (456.310 us; speedup 1.0000x reference)
//
#include <hip/hip_runtime.h>

#define N_NODES 100000
#define N_EDGES 3200000
#define SCAN_NB 391        // ceil(N_NODES/256)
#define HIST_NB 1563       // ceil(N_EDGES/8/256)
#define G1_NB   1563       // ceil(N_NODES/64)

typedef unsigned int uint;
typedef unsigned short ushort;

typedef __attribute__((ext_vector_type(8))) short short8;    // 8 bf16 (4 VGPRs)
typedef __attribute__((ext_vector_type(4))) float floatx4;   // MFMA C/D

static __device__ __forceinline__ ushort f2bf(float f) {     // RNE
    uint u = __float_as_uint(f);
    u += 0x7fffu + ((u >> 16) & 1u);
    return (ushort)(u >> 16);
}
static __device__ __forceinline__ float bf2f(ushort h) {
    return __uint_as_float(((uint)h) << 16);
}

// ---------------- prep: w1cvt (blocks 0..127) + zero deg (blocks 128..518) ----------------
// w1f layout: dest t: j=t&7, lane=(t>>3)&63, tile=t>>9; kt=tile>>2, nt=tile&3
// src: k = kt*32 + (lane>>4)*8 + j ; n = nt*16 + (lane&15)
__global__ __launch_bounds__(256) void prep_kernel(const float* __restrict__ W1,
                                                   ushort* __restrict__ W1f,
                                                   int* __restrict__ deg) {
    if (blockIdx.x < 128) {
        int t = blockIdx.x * 256 + threadIdx.x;   // 0..32767
        int j = t & 7;
        int lane = (t >> 3) & 63;
        int tile = t >> 9;
        int kt = tile >> 2, nt = tile & 3;
        int k = kt * 32 + ((lane >> 4) << 3) + j;
        int n = nt * 16 + (lane & 15);
        W1f[t] = f2bf(W1[k * 64 + n]);
    } else {
        int i = (blockIdx.x - 128) * 256 + threadIdx.x;
        if (i < N_NODES) deg[i] = 0;
    }
}

// ---------------- fused: hist (blocks 0..HIST_NB-1) | gemm1 MFMA (rest) ----------------
__global__ __launch_bounds__(256) void fused_g1_hist_kernel(const float* __restrict__ X,
                                                            const ushort* __restrict__ W1f,
                                                            ushort* __restrict__ H1,
                                                            const int* __restrict__ row,
                                                            int* __restrict__ deg,
                                                            int* __restrict__ rank) {
    if (blockIdx.x < HIST_NB) {
        // ---- histogram + rank ----
        const long base = ((long)blockIdx.x * 256 + threadIdx.x) * 8;
        if (base >= N_EDGES) return;
        int4 r0 = *reinterpret_cast<const int4*>(row + base);
        int4 r1 = *reinterpret_cast<const int4*>(row + base + 4);
        int4 k0, k1;
        k0.x = atomicAdd(&deg[r0.x], 1);
        k0.y = atomicAdd(&deg[r0.y], 1);
        k0.z = atomicAdd(&deg[r0.z], 1);
        k0.w = atomicAdd(&deg[r0.w], 1);
        k1.x = atomicAdd(&deg[r1.x], 1);
        k1.y = atomicAdd(&deg[r1.y], 1);
        k1.z = atomicAdd(&deg[r1.z], 1);
        k1.w = atomicAdd(&deg[r1.w], 1);
        *reinterpret_cast<int4*>(rank + base) = k0;
        *reinterpret_cast<int4*>(rank + base + 4) = k1;
    } else {
        // ---- gemm1: H1[64 rows x 64 cols] per block, 4 waves, no LDS ----
        const int bid = blockIdx.x - HIST_NB;
        const int tid = threadIdx.x;
        const int wave = tid >> 6;
        const int lane = tid & 63;
        const int arow = bid * 64 + wave * 16 + (lane & 15);
        const bool valid = arow < N_NODES;
        const float* xr = X + (long)arow * 512 + ((lane >> 4) << 3);
        const short8* bb = reinterpret_cast<const short8*>(W1f) + lane;

        floatx4 acc0 = {0.f, 0.f, 0.f, 0.f};
        floatx4 acc1 = {0.f, 0.f, 0.f, 0.f};
        floatx4 acc2 = {0.f, 0.f, 0.f, 0.f};
        floatx4 acc3 = {0.f, 0.f, 0.f, 0.f};

        for (int kt = 0; kt < 16; ++kt) {
            float4 ax0, ax1;
            if (valid) {
                ax0 = *reinterpret_cast<const float4*>(xr + kt * 32);
                ax1 = *reinterpret_cast<const float4*>(xr + kt * 32 + 4);
            } else {
                ax0 = make_float4(0.f, 0.f, 0.f, 0.f);
                ax1 = ax0;
            }
            uint4 ap;
            ap.x = (__float_as_uint(ax0.x) >> 16) | (__float_as_uint(ax0.y) & 0xffff0000u);
            ap.y = (__float_as_uint(ax0.z) >> 16) | (__float_as_uint(ax0.w) & 0xffff0000u);
            ap.z = (__float_as_uint(ax1.x) >> 16) | (__float_as_uint(ax1.y) & 0xffff0000u);
            ap.w = (__float_as_uint(ax1.z) >> 16) | (__float_as_uint(ax1.w) & 0xffff0000u);
            short8 a = *reinterpret_cast<short8*>(&ap);

            const short8* bk = bb + kt * 4 * 64;
            acc0 = __builtin_amdgcn_mfma_f32_16x16x32_bf16(a, bk[0 * 64], acc0, 0, 0, 0);
            acc1 = __builtin_amdgcn_mfma_f32_16x16x32_bf16(a, bk[1 * 64], acc1, 0, 0, 0);
            acc2 = __builtin_amdgcn_mfma_f32_16x16x32_bf16(a, bk[2 * 64], acc2, 0, 0, 0);
            acc3 = __builtin_amdgcn_mfma_f32_16x16x32_bf16(a, bk[3 * 64], acc3, 0, 0, 0);
        }

        const int mrow = bid * 64 + wave * 16 + (lane >> 4) * 4;
        const int ncol = lane & 15;
        #pragma unroll
        for (int r = 0; r < 4; ++r) {
            int orow = mrow + r;
            if (orow < N_NODES) {
                ushort* o = H1 + (long)orow * 64 + ncol;
                o[0]  = f2bf(acc0[r]);
                o[16] = f2bf(acc1[r]);
                o[32] = f2bf(acc2[r]);
                o[48] = f2bf(acc3[r]);
            }
        }
    }
}

// ---------------- scans ----------------
__global__ __launch_bounds__(256) void scan_a_kernel(const int* __restrict__ deg,
                                                     int* __restrict__ rowptr,
                                                     int* __restrict__ partials) {
    __shared__ int sm[256];
    const int tid = threadIdx.x;
    const int i = blockIdx.x * 256 + tid;
    int v = (i < N_NODES) ? deg[i] : 0;
    sm[tid] = v;
    __syncthreads();
    #pragma unroll
    for (int off = 1; off < 256; off <<= 1) {
        int t = (tid >= off) ? sm[tid - off] : 0;
        __syncthreads();
        sm[tid] += t;
        __syncthreads();
    }
    if (i < N_NODES) rowptr[i] = sm[tid] - v;
    if (tid == 255) partials[blockIdx.x] = sm[255];
}

__global__ __launch_bounds__(512) void scan_b_kernel(int* __restrict__ partials,
                                                     int* __restrict__ rowptr) {
    __shared__ int sm[512];
    const int tid = threadIdx.x;
    int v = (tid < SCAN_NB) ? partials[tid] : 0;
    sm[tid] = v;
    __syncthreads();
    #pragma unroll
    for (int off = 1; off < 512; off <<= 1) {
        int t = (tid >= off) ? sm[tid - off] : 0;
        __syncthreads();
        sm[tid] += t;
        __syncthreads();
    }
    if (tid < SCAN_NB) partials[tid] = sm[tid] - v;
    if (tid == 511) rowptr[N_NODES] = sm[511];
}

__global__ __launch_bounds__(256) void scan_c_kernel(int* __restrict__ rowptr,
                                                     const int* __restrict__ partials) {
    int i = blockIdx.x * 256 + threadIdx.x;
    if (i < N_NODES) rowptr[i] += partials[blockIdx.x];
}

// ---------------- scatter (atomic-free) ----------------
__global__ __launch_bounds__(256) void scatter_kernel(const int* __restrict__ row,
                                                      const int* __restrict__ col,
                                                      const float* __restrict__ val,
                                                      const int* __restrict__ rowptr,
                                                      const int* __restrict__ rank,
                                                      int2* __restrict__ edges) {
    const long base = ((long)blockIdx.x * 256 + threadIdx.x) * 8;
    if (base >= N_EDGES) return;
    int4 r0 = *reinterpret_cast<const int4*>(row + base);
    int4 r1 = *reinterpret_cast<const int4*>(row + base + 4);
    int4 c0 = *reinterpret_cast<const int4*>(col + base);
    int4 c1 = *reinterpret_cast<const int4*>(col + base + 4);
    int4 v0 = *reinterpret_cast<const int4*>(reinterpret_cast<const int*>(val) + base);
    int4 v1 = *reinterpret_cast<const int4*>(reinterpret_cast<const int*>(val) + base + 4);
    int4 k0 = *reinterpret_cast<const int4*>(rank + base);
    int4 k1 = *reinterpret_cast<const int4*>(rank + base + 4);
    int s0 = rowptr[r0.x] + k0.x;
    int s1 = rowptr[r0.y] + k0.y;
    int s2 = rowptr[r0.z] + k0.z;
    int s3 = rowptr[r0.w] + k0.w;
    int s4 = rowptr[r1.x] + k1.x;
    int s5 = rowptr[r1.y] + k1.y;
    int s6 = rowptr[r1.z] + k1.z;
    int s7 = rowptr[r1.w] + k1.w;
    edges[s0] = make_int2(c0.x, v0.x);
    edges[s1] = make_int2(c0.y, v0.y);
    edges[s2] = make_int2(c0.z, v0.z);
    edges[s3] = make_int2(c0.w, v0.w);
    edges[s4] = make_int2(c1.x, v1.x);
    edges[s5] = make_int2(c1.y, v1.y);
    edges[s6] = make_int2(c1.z, v1.z);
    edges[s7] = make_int2(c1.w, v1.w);
}

// ---------------- SPMM1 + relu + W2 fused: h3[r,0:40] = relu(A@H1)[r,:] @ W2 ----------------
// 4 waves/block, one row per wave; W2 in LDS; h2 row never materialized.
__global__ __launch_bounds__(256) void spmm1_w2_kernel(const int* __restrict__ rowptr,
                                                       const int2* __restrict__ edges,
                                                       const ushort* __restrict__ H1,
                                                       const float* __restrict__ W2,
                                                       ushort* __restrict__ H3) {
    __shared__ float Ws[64 * 40];
    __shared__ float hrow[4][64];
    for (int i = threadIdx.x; i < 64 * 40; i += 256) Ws[i] = W2[i];
    __syncthreads();

    const int r = blockIdx.x * 4 + (threadIdx.x >> 6);
    const int wave = threadIdx.x >> 6;
    const int lane = threadIdx.x & 63;
    if (r >= N_NODES) return;

    const int start = rowptr[r];
    const int end = rowptr[r + 1];
    float acc = 0.f;
    for (int base = start; base < end; base += 64) {
        const int n = end - base;
        int c = 0;
        float v = 0.f;
        if (lane < n) {
            int2 ev = edges[base + lane];
            c = ev.x;
            v = __int_as_float(ev.y);
        }
        const int cnt = n < 64 ? n : 64;
        const int cnt4 = (cnt + 3) & ~3;
        for (int j = 0; j < cnt4; j += 4) {
            int c0 = __builtin_amdgcn_readlane(c, j);
            int c1 = __builtin_amdgcn_readlane(c, j + 1);
            int c2 = __builtin_amdgcn_readlane(c, j + 2);
            int c3 = __builtin_amdgcn_readlane(c, j + 3);
            float v0 = __int_as_float(__builtin_amdgcn_readlane(__float_as_int(v), j));
            float v1 = __int_as_float(__builtin_amdgcn_readlane(__float_as_int(v), j + 1));
            float v2 = __int_as_float(__builtin_amdgcn_readlane(__float_as_int(v), j + 2));
            float v3 = __int_as_float(__builtin_amdgcn_readlane(__float_as_int(v), j + 3));
            ushort h0 = H1[(long)c0 * 64 + lane];
            ushort h1 = H1[(long)c1 * 64 + lane];
            ushort h2 = H1[(long)c2 * 64 + lane];
            ushort h3 = H1[(long)c3 * 64 + lane];
            acc += v0 * bf2f(h0);
            acc += v1 * bf2f(h1);
            acc += v2 * bf2f(h2);
            acc += v3 * bf2f(h3);
        }
    }
    // relu, stash row in wave-private LDS, then x@W2 epilogue
    hrow[wave][lane] = fmaxf(acc, 0.f);
    float o = 0.f;
    if (lane < 40) {
        #pragma unroll
        for (int k = 0; k < 64; ++k) o += hrow[wave][k] * Ws[k * 40 + lane];
        H3[(long)r * 40 + lane] = f2bf(o);
    }
}

// ---------------- SPMM2: out[r,0:40] = (A@H3)[r,:] ----------------
__global__ __launch_bounds__(256) void spmm2_kernel(const int* __restrict__ rowptr,
                                                    const int2* __restrict__ edges,
                                                    const ushort* __restrict__ H,
                                                    float* __restrict__ O) {
    const int r = blockIdx.x * 4 + (threadIdx.x >> 6);
    if (r >= N_NODES) return;
    const int lane = threadIdx.x & 63;
    const int start = rowptr[r];
    const int end = rowptr[r + 1];
    float acc = 0.f;
    for (int base = start; base < end; base += 64) {
        const int n = end - base;
        int c = 0;
        float v = 0.f;
        if (lane < n) {
            int2 ev = edges[base + lane];
            c = ev.x;
            v = __int_as_float(ev.y);
        }
        const int cnt = n < 64 ? n : 64;
        const int cnt4 = (cnt + 3) & ~3;
        for (int j = 0; j < cnt4; j += 4) {
            int c0 = __builtin_amdgcn_readlane(c, j);
            int c1 = __builtin_amdgcn_readlane(c, j + 1);
            int c2 = __builtin_amdgcn_readlane(c, j + 2);
            int c3 = __builtin_amdgcn_readlane(c, j + 3);
            float v0 = __int_as_float(__builtin_amdgcn_readlane(__float_as_int(v), j));
            float v1 = __int_as_float(__builtin_amdgcn_readlane(__float_as_int(v), j + 1));
            float v2 = __int_as_float(__builtin_amdgcn_readlane(__float_as_int(v), j + 2));
            float v3 = __int_as_float(__builtin_amdgcn_readlane(__float_as_int(v), j + 3));
            ushort h0 = H[(long)c0 * 40 + lane];
            ushort h1 = H[(long)c1 * 40 + lane];
            ushort h2 = H[(long)c2 * 40 + lane];
            ushort h3 = H[(long)c3 * 40 + lane];
            acc += v0 * bf2f(h0);
            acc += v1 * bf2f(h1);
            acc += v2 * bf2f(h2);
            acc += v3 * bf2f(h3);
        }
    }
    if (lane < 40) O[(long)r * 40 + lane] = acc;
}

extern "C" void kernel_launch(void* const* d_in, const int* in_sizes, int n_in,
                              void* d_out, int out_size, void* d_ws, size_t ws_size,
                              hipStream_t stream) {
    const float* x       = (const float*)d_in[0];
    const float* W1      = (const float*)d_in[1];
    const float* W2      = (const float*)d_in[2];
    const float* adj_val = (const float*)d_in[3];
    const int*   adj_row = (const int*)d_in[4];
    const int*   adj_col = (const int*)d_in[5];
    float* out = (float*)d_out;

    char* ws = (char*)d_ws;
    const size_t OFF_H1     = 0;            // bf16 h1: 12.8 MB
    const size_t OFF_H3     = 12800000;     // bf16 h3: 8 MB
    const size_t OFF_EDGES  = 20800000;     // int2 edges: 25.6 MB
    const size_t OFF_RANK   = 46400000;     // int rank: 12.8 MB
    const size_t OFF_ROWPTR = 59200000;     // 400,004 B
    const size_t OFF_DEG    = 59600016;     // 400,000 B
    const size_t OFF_PART   = 60000016;     // 2,048 B
    const size_t OFF_W1F    = 60002064;     // bf16 frag-ordered W1: 65,536 B (16B aligned)

    ushort* h1     = (ushort*)(ws + OFF_H1);
    ushort* h3     = (ushort*)(ws + OFF_H3);
    int2*   edges  = (int2*)(ws + OFF_EDGES);
    int*    rank   = (int*)(ws + OFF_RANK);
    int*    rowptr = (int*)(ws + OFF_ROWPTR);
    int*    deg    = (int*)(ws + OFF_DEG);
    int*    part   = (int*)(ws + OFF_PART);
    ushort* w1f    = (ushort*)(ws + OFF_W1F);

    // prep: w1cvt + zero deg
    prep_kernel<<<128 + SCAN_NB, 256, 0, stream>>>(W1, w1f, deg);

    // fused: hist (atomic-RMW bound) co-resident with gemm1 (HBM/MFMA bound)
    fused_g1_hist_kernel<<<HIST_NB + G1_NB, 256, 0, stream>>>(x, w1f, h1, adj_row, deg, rank);

    // scans
    scan_a_kernel<<<SCAN_NB, 256, 0, stream>>>(deg, rowptr, part);
    scan_b_kernel<<<1, 512, 0, stream>>>(part, rowptr);
    scan_c_kernel<<<SCAN_NB, 256, 0, stream>>>(rowptr, part);

    // scatter
    scatter_kernel<<<HIST_NB, 256, 0, stream>>>(adj_row, adj_col, adj_val, rowptr, rank, edges);

    // spmm1 + relu + W2 (h2 never materialized)
    spmm1_w2_kernel<<<(N_NODES + 3) / 4, 256, 0, stream>>>(rowptr, edges, h1, W2, h3);

    // spmm2
    spmm2_kernel<<<(N_NODES + 3) / 4, 256, 0, stream>>>(rowptr, edges, h3, out);
}

// Round 7
// 327.914 us; speedup vs baseline: 1.3916x; 1.3916x over previous
//
#include <hip/hip_runtime.h>

#define N_NODES 100000
#define N_EDGES 3200000
#define CH      12500      // edges per chunk (C1/C3)
#define C_NB    256        // chunks; C_NB*CH == N_EDGES exactly
#define NBUCK   782        // ceil(N_NODES/128)
#define G1_NB   1563       // ceil(N_NODES/64)

typedef unsigned int uint;
typedef unsigned short ushort;

typedef __attribute__((ext_vector_type(8))) short short8;    // 8 bf16 (4 VGPRs)
typedef __attribute__((ext_vector_type(4))) float floatx4;   // MFMA C/D

static __device__ __forceinline__ ushort f2bf(float f) {     // RNE
    uint u = __float_as_uint(f);
    u += 0x7fffu + ((u >> 16) & 1u);
    return (ushort)(u >> 16);
}
static __device__ __forceinline__ float bf2f(ushort h) {
    return __uint_as_float(((uint)h) << 16);
}

// ---------------- prep: w1cvt (blocks 0..127) + zero coarse_count ----------------
__global__ __launch_bounds__(256) void prep_kernel(const float* __restrict__ W1,
                                                   ushort* __restrict__ W1f,
                                                   int* __restrict__ cc) {
    if (blockIdx.x < 128) {
        int t = blockIdx.x * 256 + threadIdx.x;   // 0..32767
        int j = t & 7;
        int lane = (t >> 3) & 63;
        int tile = t >> 9;
        int kt = tile >> 2, nt = tile & 3;
        int k = kt * 32 + ((lane >> 4) << 3) + j;
        int n = nt * 16 + (lane & 15);
        W1f[t] = f2bf(W1[k * 64 + n]);
    } else {
        int i = (blockIdx.x - 128) * 256 + threadIdx.x;
        if (i < NBUCK) cc[i] = 0;
    }
}

// ---------------- fused: C1 coarse hist (blocks 0..C_NB-1) | gemm1 MFMA ----------------
__global__ __launch_bounds__(256) void fused_g1_c1_kernel(const float* __restrict__ X,
                                                          const ushort* __restrict__ W1f,
                                                          ushort* __restrict__ H1,
                                                          const int* __restrict__ row,
                                                          int* __restrict__ cc,
                                                          int* __restrict__ blockbase) {
    __shared__ int hist[NBUCK];
    if (blockIdx.x < C_NB) {
        const int blk = blockIdx.x;
        for (int i = threadIdx.x; i < NBUCK; i += 256) hist[i] = 0;
        __syncthreads();
        const int4* rp = reinterpret_cast<const int4*>(row + (long)blk * CH);
        for (int i = threadIdx.x; i < CH / 4; i += 256) {
            int4 r = rp[i];
            atomicAdd(&hist[r.x >> 7], 1);
            atomicAdd(&hist[r.y >> 7], 1);
            atomicAdd(&hist[r.z >> 7], 1);
            atomicAdd(&hist[r.w >> 7], 1);
        }
        __syncthreads();
        for (int i = threadIdx.x; i < NBUCK; i += 256) {
            int c = hist[i];
            int base = 0;
            if (c) base = atomicAdd(&cc[i], c);
            blockbase[blk * NBUCK + i] = base;
        }
    } else {
        // ---- gemm1: H1[64 rows x 64 cols] per block, 4 waves, no LDS ----
        const int bid = blockIdx.x - C_NB;
        const int tid = threadIdx.x;
        const int wave = tid >> 6;
        const int lane = tid & 63;
        const int arow = bid * 64 + wave * 16 + (lane & 15);
        const bool valid = arow < N_NODES;
        const float* xr = X + (long)arow * 512 + ((lane >> 4) << 3);
        const short8* bb = reinterpret_cast<const short8*>(W1f) + lane;

        floatx4 acc0 = {0.f, 0.f, 0.f, 0.f};
        floatx4 acc1 = {0.f, 0.f, 0.f, 0.f};
        floatx4 acc2 = {0.f, 0.f, 0.f, 0.f};
        floatx4 acc3 = {0.f, 0.f, 0.f, 0.f};

        for (int kt = 0; kt < 16; ++kt) {
            float4 ax0, ax1;
            if (valid) {
                ax0 = *reinterpret_cast<const float4*>(xr + kt * 32);
                ax1 = *reinterpret_cast<const float4*>(xr + kt * 32 + 4);
            } else {
                ax0 = make_float4(0.f, 0.f, 0.f, 0.f);
                ax1 = ax0;
            }
            uint4 ap;
            ap.x = (__float_as_uint(ax0.x) >> 16) | (__float_as_uint(ax0.y) & 0xffff0000u);
            ap.y = (__float_as_uint(ax0.z) >> 16) | (__float_as_uint(ax0.w) & 0xffff0000u);
            ap.z = (__float_as_uint(ax1.x) >> 16) | (__float_as_uint(ax1.y) & 0xffff0000u);
            ap.w = (__float_as_uint(ax1.z) >> 16) | (__float_as_uint(ax1.w) & 0xffff0000u);
            short8 a = *reinterpret_cast<short8*>(&ap);

            const short8* bk = bb + kt * 4 * 64;
            acc0 = __builtin_amdgcn_mfma_f32_16x16x32_bf16(a, bk[0 * 64], acc0, 0, 0, 0);
            acc1 = __builtin_amdgcn_mfma_f32_16x16x32_bf16(a, bk[1 * 64], acc1, 0, 0, 0);
            acc2 = __builtin_amdgcn_mfma_f32_16x16x32_bf16(a, bk[2 * 64], acc2, 0, 0, 0);
            acc3 = __builtin_amdgcn_mfma_f32_16x16x32_bf16(a, bk[3 * 64], acc3, 0, 0, 0);
        }

        const int mrow = bid * 64 + wave * 16 + (lane >> 4) * 4;
        const int ncol = lane & 15;
        #pragma unroll
        for (int r = 0; r < 4; ++r) {
            int orow = mrow + r;
            if (orow < N_NODES) {
                ushort* o = H1 + (long)orow * 64 + ncol;
                o[0]  = f2bf(acc0[r]);
                o[16] = f2bf(acc1[r]);
                o[32] = f2bf(acc2[r]);
                o[48] = f2bf(acc3[r]);
            }
        }
    }
}

// ---------------- C2: scan of 782 coarse counts ----------------
__global__ __launch_bounds__(1024) void c2_scan_kernel(const int* __restrict__ cc,
                                                       int* __restrict__ cptr) {
    __shared__ int sm[1024];
    const int tid = threadIdx.x;
    int v = (tid < NBUCK) ? cc[tid] : 0;
    sm[tid] = v;
    __syncthreads();
    #pragma unroll
    for (int off = 1; off < 1024; off <<= 1) {
        int t = (tid >= off) ? sm[tid - off] : 0;
        __syncthreads();
        sm[tid] += t;
        __syncthreads();
    }
    if (tid < NBUCK) cptr[tid] = sm[tid] - v;        // exclusive
    if (tid == NBUCK - 1) cptr[NBUCK] = sm[tid];     // total = N_EDGES
}

// ---------------- C3: bucket scatter (LDS ranks, block-local runs) ----------------
__global__ __launch_bounds__(256) void c3_kernel(const int* __restrict__ row,
                                                 const int* __restrict__ col,
                                                 const float* __restrict__ val,
                                                 const int* __restrict__ cptr,
                                                 const int* __restrict__ blockbase,
                                                 int2* __restrict__ staging) {
    __shared__ int cnt[NBUCK];
    const int blk = blockIdx.x;
    for (int i = threadIdx.x; i < NBUCK; i += 256) cnt[i] = 0;
    __syncthreads();
    const long e0 = (long)blk * CH;
    const int4* rp = reinterpret_cast<const int4*>(row + e0);
    const int4* cp = reinterpret_cast<const int4*>(col + e0);
    const int4* vp = reinterpret_cast<const int4*>(reinterpret_cast<const int*>(val) + e0);
    const int* bb = blockbase + blk * NBUCK;
    for (int i = threadIdx.x; i < CH / 4; i += 256) {
        int4 r = rp[i];
        int4 c = cp[i];
        int4 v = vp[i];
        #pragma unroll
        for (int q = 0; q < 4; ++q) {
            int rr = (q == 0) ? r.x : (q == 1) ? r.y : (q == 2) ? r.z : r.w;
            int ccol = (q == 0) ? c.x : (q == 1) ? c.y : (q == 2) ? c.z : c.w;
            int vv = (q == 0) ? v.x : (q == 1) ? v.y : (q == 2) ? v.z : v.w;
            int b = rr >> 7;
            int lr = atomicAdd(&cnt[b], 1);
            int slot = cptr[b] + bb[b] + lr;
            staging[slot] = make_int2((ccol << 7) | (rr & 127), vv);
        }
    }
}

// ---------------- C4: per-bucket 128-bin sort -> rowptr + final CSR ----------------
__global__ __launch_bounds__(256) void c4_kernel(const int* __restrict__ cptr,
                                                 const int2* __restrict__ staging,
                                                 int2* __restrict__ edges,
                                                 int* __restrict__ rowptr) {
    __shared__ int cnt[128];
    __shared__ int sc[128];
    __shared__ int excl[129];
    __shared__ int cur[128];
    const int b = blockIdx.x;
    const int tid = threadIdx.x;
    const int lo = cptr[b], hi = cptr[b + 1];

    if (tid < 128) cnt[tid] = 0;
    __syncthreads();
    for (int i = lo + tid; i < hi; i += 256) atomicAdd(&cnt[staging[i].x & 127], 1);
    __syncthreads();
    if (tid < 128) sc[tid] = cnt[tid];
    __syncthreads();
    #pragma unroll
    for (int off = 1; off < 128; off <<= 1) {
        int t = 0;
        if (tid < 128 && tid >= off) t = sc[tid - off];
        __syncthreads();
        if (tid < 128) sc[tid] += t;
        __syncthreads();
    }
    if (tid < 128) {
        excl[tid] = sc[tid] - cnt[tid];
        cur[tid] = sc[tid] - cnt[tid];
    }
    if (tid == 127) excl[128] = sc[127];
    __syncthreads();
    if (tid <= 128) {
        int gr = b * 128 + tid;
        if (gr <= N_NODES) rowptr[gr] = lo + excl[tid];
    }
    __syncthreads();
    for (int i = lo + tid; i < hi; i += 256) {
        int2 ev = staging[i];
        int pos = atomicAdd(&cur[ev.x & 127], 1);
        edges[lo + pos] = make_int2(ev.x >> 7, ev.y);
    }
}

// ---------------- SPMM1 + relu + W2 fused: h3[r,0:40] = relu(A@H1)[r,:] @ W2 ----------------
__global__ __launch_bounds__(256) void spmm1_w2_kernel(const int* __restrict__ rowptr,
                                                       const int2* __restrict__ edges,
                                                       const ushort* __restrict__ H1,
                                                       const float* __restrict__ W2,
                                                       ushort* __restrict__ H3) {
    __shared__ float Ws[64 * 40];
    __shared__ float hrow[4][64];
    for (int i = threadIdx.x; i < 64 * 40; i += 256) Ws[i] = W2[i];
    __syncthreads();

    const int r = blockIdx.x * 4 + (threadIdx.x >> 6);
    const int wave = threadIdx.x >> 6;
    const int lane = threadIdx.x & 63;
    if (r >= N_NODES) return;

    const int start = rowptr[r];
    const int end = rowptr[r + 1];
    float acc = 0.f;
    for (int base = start; base < end; base += 64) {
        const int n = end - base;
        int c = 0;
        float v = 0.f;
        if (lane < n) {
            int2 ev = edges[base + lane];
            c = ev.x;
            v = __int_as_float(ev.y);
        }
        const int cnt = n < 64 ? n : 64;
        const int cnt4 = (cnt + 3) & ~3;
        for (int j = 0; j < cnt4; j += 4) {
            int c0 = __builtin_amdgcn_readlane(c, j);
            int c1 = __builtin_amdgcn_readlane(c, j + 1);
            int c2 = __builtin_amdgcn_readlane(c, j + 2);
            int c3 = __builtin_amdgcn_readlane(c, j + 3);
            float v0 = __int_as_float(__builtin_amdgcn_readlane(__float_as_int(v), j));
            float v1 = __int_as_float(__builtin_amdgcn_readlane(__float_as_int(v), j + 1));
            float v2 = __int_as_float(__builtin_amdgcn_readlane(__float_as_int(v), j + 2));
            float v3 = __int_as_float(__builtin_amdgcn_readlane(__float_as_int(v), j + 3));
            ushort h0 = H1[(long)c0 * 64 + lane];
            ushort h1 = H1[(long)c1 * 64 + lane];
            ushort h2 = H1[(long)c2 * 64 + lane];
            ushort h3 = H1[(long)c3 * 64 + lane];
            acc += v0 * bf2f(h0);
            acc += v1 * bf2f(h1);
            acc += v2 * bf2f(h2);
            acc += v3 * bf2f(h3);
        }
    }
    hrow[wave][lane] = fmaxf(acc, 0.f);
    float o = 0.f;
    if (lane < 40) {
        #pragma unroll
        for (int k = 0; k < 64; ++k) o += hrow[wave][k] * Ws[k * 40 + lane];
        H3[(long)r * 40 + lane] = f2bf(o);
    }
}

// ---------------- SPMM2: out[r,0:40] = (A@H3)[r,:] ----------------
__global__ __launch_bounds__(256) void spmm2_kernel(const int* __restrict__ rowptr,
                                                    const int2* __restrict__ edges,
                                                    const ushort* __restrict__ H,
                                                    float* __restrict__ O) {
    const int r = blockIdx.x * 4 + (threadIdx.x >> 6);
    if (r >= N_NODES) return;
    const int lane = threadIdx.x & 63;
    const int start = rowptr[r];
    const int end = rowptr[r + 1];
    float acc = 0.f;
    for (int base = start; base < end; base += 64) {
        const int n = end - base;
        int c = 0;
        float v = 0.f;
        if (lane < n) {
            int2 ev = edges[base + lane];
            c = ev.x;
            v = __int_as_float(ev.y);
        }
        const int cnt = n < 64 ? n : 64;
        const int cnt4 = (cnt + 3) & ~3;
        for (int j = 0; j < cnt4; j += 4) {
            int c0 = __builtin_amdgcn_readlane(c, j);
            int c1 = __builtin_amdgcn_readlane(c, j + 1);
            int c2 = __builtin_amdgcn_readlane(c, j + 2);
            int c3 = __builtin_amdgcn_readlane(c, j + 3);
            float v0 = __int_as_float(__builtin_amdgcn_readlane(__float_as_int(v), j));
            float v1 = __int_as_float(__builtin_amdgcn_readlane(__float_as_int(v), j + 1));
            float v2 = __int_as_float(__builtin_amdgcn_readlane(__float_as_int(v), j + 2));
            float v3 = __int_as_float(__builtin_amdgcn_readlane(__float_as_int(v), j + 3));
            ushort h0 = H[(long)c0 * 40 + lane];
            ushort h1 = H[(long)c1 * 40 + lane];
            ushort h2 = H[(long)c2 * 40 + lane];
            ushort h3 = H[(long)c3 * 40 + lane];
            acc += v0 * bf2f(h0);
            acc += v1 * bf2f(h1);
            acc += v2 * bf2f(h2);
            acc += v3 * bf2f(h3);
        }
    }
    if (lane < 40) O[(long)r * 40 + lane] = acc;
}

extern "C" void kernel_launch(void* const* d_in, const int* in_sizes, int n_in,
                              void* d_out, int out_size, void* d_ws, size_t ws_size,
                              hipStream_t stream) {
    const float* x       = (const float*)d_in[0];
    const float* W1      = (const float*)d_in[1];
    const float* W2      = (const float*)d_in[2];
    const float* adj_val = (const float*)d_in[3];
    const int*   adj_row = (const int*)d_in[4];
    const int*   adj_col = (const int*)d_in[5];
    float* out = (float*)d_out;

    char* ws = (char*)d_ws;
    const size_t OFF_H1     = 0;             // bf16 h1: 12.8 MB
    const size_t OFF_STG    = 12800000;      // int2 staging: 25.6 MB (h3 overlays after C4)
    const size_t OFF_H3     = 12800000;      // bf16 h3: 8 MB (overlays staging)
    const size_t OFF_EDGES  = 38400000;      // int2 edges: 25.6 MB
    const size_t OFF_ROWPTR = 64000000;      // 400,016 B
    const size_t OFF_CC     = 64400016;      // 782*4 -> 3,136 B
    const size_t OFF_CPTR   = 64403152;      // 783*4 -> 3,136 B
    const size_t OFF_BB     = 64406288;      // 256*782*4 = 800,768 B
    const size_t OFF_W1F    = 65207056;      // 65,536 B (16B aligned)

    ushort* h1     = (ushort*)(ws + OFF_H1);
    int2*   stg    = (int2*)(ws + OFF_STG);
    ushort* h3     = (ushort*)(ws + OFF_H3);
    int2*   edges  = (int2*)(ws + OFF_EDGES);
    int*    rowptr = (int*)(ws + OFF_ROWPTR);
    int*    cc     = (int*)(ws + OFF_CC);
    int*    cptr   = (int*)(ws + OFF_CPTR);
    int*    bb     = (int*)(ws + OFF_BB);
    ushort* w1f    = (ushort*)(ws + OFF_W1F);

    // prep: w1cvt + zero coarse counts
    prep_kernel<<<128 + 4, 256, 0, stream>>>(W1, w1f, cc);

    // fused: gemm1 (MFMA, HBM-stream) | C1 coarse hist (LDS, few atomics)
    fused_g1_c1_kernel<<<C_NB + G1_NB, 256, 0, stream>>>(x, w1f, h1, adj_row, cc, bb);

    // C2: 782-wide scan
    c2_scan_kernel<<<1, 1024, 0, stream>>>(cc, cptr);

    // C3: scatter into coarse buckets (block-local runs)
    c3_kernel<<<C_NB, 256, 0, stream>>>(adj_row, adj_col, adj_val, cptr, bb, stg);

    // C4: per-bucket sort -> rowptr + final CSR (L2-local writes)
    c4_kernel<<<NBUCK, 256, 0, stream>>>(cptr, stg, edges, rowptr);

    // spmm1 + relu + W2 (h2 never materialized)
    spmm1_w2_kernel<<<(N_NODES + 3) / 4, 256, 0, stream>>>(rowptr, edges, h1, W2, h3);

    // spmm2
    spmm2_kernel<<<(N_NODES + 3) / 4, 256, 0, stream>>>(rowptr, edges, h3, out);
}